// Round 10
// baseline (125.517 us; speedup 1.0000x reference)
//
#include <hip/hip_runtime.h>
#include <math.h>

#define EPS  1e-6f
#define DD   256
#define NSUP 5
#define NQ   8
#define SEQ  13
#define L2E  1.44269504088896f
#define LN2  0.693147180559945f
#define NEP  2048            // episodes
#define NROW 16384           // NEP*NQ query rows
#define NCOL 2048            // anchor columns

typedef short bf16x8 __attribute__((ext_vector_type(8)));
typedef unsigned short u16x4 __attribute__((ext_vector_type(4)));
typedef float f32x4  __attribute__((ext_vector_type(4)));

__device__ __forceinline__ ushort f2bf(float f) {
  union { float f; unsigned u; } v; v.f = f;
  unsigned r = v.u + 0x7FFFu + ((v.u >> 16) & 1u);   // round-to-nearest-even
  return (ushort)(r >> 16);
}
__device__ __forceinline__ float bf2f(short u) {
  union { unsigned u; float f; } v; v.u = ((unsigned)(unsigned short)u) << 16;
  return v.f;
}

// ---------------------------------------------------------------------------
// prep (r8-proven, unchanged): anchors/queries in MFMA-fragment-SWIZZLED order;
// element (c,d) -> ushort idx (((c>>4)*8+(d>>5))*64 + ((d>>3)&3)*16 + (c&15))*8+(d&7).
// cb[c] = -log2(e)*(sum(a^2) - 2*eps*sum(a)); row-constant cq cancels.
// ---------------------------------------------------------------------------
__global__ __launch_bounds__(256) void proto_prep(
    const float* __restrict__ x, float* __restrict__ cb,
    ushort* __restrict__ Asw, ushort* __restrict__ Qsw,
    float* __restrict__ accum, int* __restrict__ fincount) {
  const int tid = threadIdx.x, g = tid >> 6, l = tid & 63;
  const int n = blockIdx.x * 4 + g;
  if (blockIdx.x == 0 && tid == 0) { accum[0] = 0.f; accum[1] = 0.f; fincount[0] = 0; }

  const float4* xr4 = (const float4*)(x + (size_t)n * SEQ * DD);

  const int d0   = l * 4;
  const int kk   = d0 >> 5, quad = (d0 >> 3) & 3, j = d0 & 7;   // j in {0,4}
  const size_t chunk_d = (size_t)kk * 64 + (size_t)quad * 16;

  float4 a = {0.f, 0.f, 0.f, 0.f};
  #pragma unroll
  for (int s = 0; s < NSUP; ++s) {
    float4 v = xr4[s * 64 + l];
    a.x += v.x; a.y += v.y; a.z += v.z; a.w += v.w;
  }
  a.x *= 0.2f; a.y *= 0.2f; a.z *= 0.2f; a.w *= 0.2f;
  {
    const size_t idx = (((size_t)(n >> 4) * 8) * 64 + chunk_d + (n & 15)) * 8 + j;
    u16x4 o = {f2bf(a.x), f2bf(a.y), f2bf(a.z), f2bf(a.w)};
    *(u16x4*)(Asw + idx) = o;
  }
  float s1 = a.x + a.y + a.z + a.w;
  float s2 = a.x * a.x + a.y * a.y + a.z * a.z + a.w * a.w;
  #pragma unroll
  for (int off = 32; off; off >>= 1) {
    s1 += __shfl_xor(s1, off);
    s2 += __shfl_xor(s2, off);
  }
  if (l == 0) cb[n] = -L2E * (s2 - 2.f * EPS * s1);

  #pragma unroll
  for (int s = 0; s < NQ; ++s) {
    float4 q = xr4[(NSUP + s) * 64 + l];
    const int row = n * NQ + s;
    const size_t idx = (((size_t)(row >> 4) * 8) * 64 + chunk_d + (row & 15)) * 8 + j;
    u16x4 o = {f2bf(q.x), f2bf(q.y), f2bf(q.z), f2bf(q.w)};
    *(u16x4*)(Qsw + idx) = o;
  }
}

// ---------------------------------------------------------------------------
// main r22: MINIMAL-FLOW TILE. r21 validated the per-CU operand-flow model:
// halving B-flow (1 MB -> 512 KB) cut proto_main 51 -> <43.6 us (dropped out
// of the rocprof top-5, below the 44 us ws-poison fill) — first real gain in
// nine rounds, on the predicted axis. Flow = (rows + cols) x 512 B per block
// at fixed rows*cols = 131072; minimized by a square-ish tile. This round:
// block = 256 rows x 512 cols (grid 256 = 64 rb x 4 colc) -> flow = A 128 KB
// + B 256 KB = 384 KB (r21: 640 KB). Wave inner loop byte-identical again
// (af[2][8], 16 steps, 2-deep dbuf, sCb broadcast): 16 waves = 8 rowg x
// 2 colg; each colg group's 8 waves stage 1 K-chunk each per tile.
// LDS: Bl 32K + sCb 2K + merge 7K = 41 KB. VGPR ~64: no spill.
// Rows span 4 chunks -> 4-way ascending merge in proto_merge (same family
// that gave absmax 0.0 on the 2-way split); label pass = r0-proven
// 4-lanes/row x 2-kk pattern (256 rows x 4 = 1024 threads).
// MFMA layouts (verified): A m=lane&15,k=quad*8+j ; B n=lane&15,k=quad*8+j ;
// C col=lane&15,row=quad*4+reg.
// ---------------------------------------------------------------------------
__global__ __launch_bounds__(1024, 4) void proto_main(
    const ushort* __restrict__ Qsw, const ushort* __restrict__ Asw,
    const float* __restrict__ cb, const int* __restrict__ label,
    float* __restrict__ partm, float* __restrict__ parts,
    int* __restrict__ partbi, float* __restrict__ slabws) {
  const int tid  = threadIdx.x;
  const int wid  = tid >> 6, lane = tid & 63;
  const int quad = lane >> 4, lcol = lane & 15;
  const int rowg = wid & 7, colg = wid >> 3;        // 8 x 2 wave grid
  const int rb   = blockIdx.x >> 2;                 // row-block (256 rows)
  const int colc = blockIdx.x & 3;                  // col-chunk (512 cols)
  const int r0   = rb * 256;

  const bf16x8* qb = (const bf16x8*)Qsw;
  const bf16x8* bb = (const bf16x8*)Asw;

  __shared__ bf16x8 Bl[2][2][8][64];                 // 32 KiB B staging
  __shared__ float  sCb[512];                        // this chunk's col consts

  if (tid < 512) sCb[tid] = cb[colc * 512 + tid];    // one-time, coalesced

  // resident A fragments: this wave's 32 rows (2 sets) x 8 K-chunks (64 VGPR)
  bf16x8 af[2][8];
  #pragma unroll
  for (int set = 0; set < 2; ++set) {
    const size_t base = ((size_t)(rb * 16 + rowg * 2 + set) * 8) * 64 + lane;
    #pragma unroll
    for (int kk = 0; kk < 8; ++kk) af[set][kk] = qb[base + (size_t)kk * 64];
  }

  float m[2][4], s[2][4];
  int   bi[2][4];
  #pragma unroll
  for (int set = 0; set < 2; ++set)
    #pragma unroll
    for (int i = 0; i < 4; ++i) {
      m[set][i] = -1e30f; s[set][i] = 0.f; bi[set][i] = 0x7fffffff;
    }

  // wave (rowg) stages K-chunk kk=rowg of tile tl into buf b: 1 x
  // global_load_lds width=16 (linear dest: base + lane*16). [G13/T3]
  auto stage = [&](int tl, int b) {
    const int T = colc * 32 + colg * 16 + tl;        // global 16-col tile id
    const ushort* src = Asw + (((size_t)T * 8 + rowg) * 64 + lane) * 8;
    __builtin_amdgcn_global_load_lds(
        (const __attribute__((address_space(1))) void*)src,
        (__attribute__((address_space(3))) void*)&Bl[colg][b][rowg][0],
        16, 0, 0);
  };

  auto compute = [&](int tl, int b) {
    f32x4 c0 = {0.f, 0.f, 0.f, 0.f}, c1 = {0.f, 0.f, 0.f, 0.f};
    #pragma unroll
    for (int kk = 0; kk < 8; ++kk) {
      bf16x8 bf = Bl[colg][b][kk][lane];
      c0 = __builtin_amdgcn_mfma_f32_16x16x32_bf16(af[0][kk], bf, c0, 0, 0, 0);
      c1 = __builtin_amdgcn_mfma_f32_16x16x32_bf16(af[1][kk], bf, c1, 0, 0, 0);
    }
    const int   lcIdx  = (colg * 16 + tl) * 16 + lcol;   // chunk-local col
    const int   colIdx = colc * 512 + lcIdx;             // global col (for bi)
    const float cbv    = sCb[lcIdx];                     // LDS broadcast
    #pragma unroll
    for (int set = 0; set < 2; ++set) {
      #pragma unroll
      for (int i = 0; i < 4; ++i) {
        float cv = set ? c1[i] : c0[i];
        float v2 = fmaf(cv, 2.f * L2E, cbv);         // log2-frame shifted logit
        float dv = v2 - m[set][i];
        bool  gt = dv > 0.f;
        float e  = exp2f(-fabsf(dv));                // single non-unit exp factor
        s[set][i]  = fmaf(s[set][i], gt ? e : 1.f, gt ? 1.f : e);
        m[set][i]  = fmaxf(m[set][i], v2);
        bi[set][i] = gt ? colIdx : bi[set][i];       // strict >: first max wins
      }
    }
  };

  stage(0, 0);
  __syncthreads();                                   // tile 0 + sCb ready

  #pragma unroll 1
  for (int t = 0; t < 16; t += 2) {
    stage(t + 1, 1);                                 // t+1 always < 16
    compute(t, 0);
    __syncthreads();                                 // t+1 staged; buf0 free
    if (t + 2 < 16) stage(t + 2, 0);
    compute(t + 1, 1);
    __syncthreads();                                 // t+2 staged; buf1 free
  }

  // merge across the 16 lanes sharing rows (cols differ)
  #pragma unroll
  for (int mask = 1; mask < 16; mask <<= 1) {
    #pragma unroll
    for (int set = 0; set < 2; ++set)
      #pragma unroll
      for (int i = 0; i < 4; ++i) {
        float om = __shfl_xor(m[set][i], mask);
        float os = __shfl_xor(s[set][i], mask);
        int   oi = __shfl_xor(bi[set][i], mask);
        float nm = fmaxf(m[set][i], om);
        s[set][i] = s[set][i] * exp2f(m[set][i] - nm) + os * exp2f(om - nm);
        bool better = (om > m[set][i]) || (om == m[set][i] && oi < bi[set][i]);
        bi[set][i] = better ? oi : bi[set][i];
        m[set][i]  = nm;
      }
  }

  __shared__ float sm[2][256], ssh[2][256];
  __shared__ int   sbi[2][256];
  if (lcol == 0) {
    #pragma unroll
    for (int set = 0; set < 2; ++set)
      #pragma unroll
      for (int i = 0; i < 4; ++i) {
        int rl = rowg * 32 + set * 16 + quad * 4 + i;
        sm[colg][rl] = m[set][i]; ssh[colg][rl] = s[set][i]; sbi[colg][rl] = bi[set][i];
      }
  }
  __syncthreads();

  // in-block merge over the 2 colg stripes (ascending cols) -> ws partials
  if (tid < 256) {
    float mm = sm[0][tid], sv = ssh[0][tid];
    int   b  = sbi[0][tid];
    {
      float om = sm[1][tid], os = ssh[1][tid];
      int   oi = sbi[1][tid];
      float nm = fmaxf(mm, om);
      sv = sv * exp2f(mm - nm) + os * exp2f(om - nm);
      bool better = (om > mm) || (om == mm && oi < b);
      b = better ? oi : b;
      mm = nm;
    }
    const int row = r0 + tid;
    partm [colc * NROW + row] = mm;
    parts [colc * NROW + row] = sv;
    partbi[colc * NROW + row] = b;
  }

  // label-logit pass (r11-proven 4-lane pattern), colc==0 blocks only:
  // 4 lanes/row x 256 rows = 1024 threads; lane l handles K-chunks {2l,2l+1}.
  if (colc == 0) {
    const int rl = tid >> 2, l = tid & 3;
    const int row = r0 + rl;
    const int lab = label[row >> 3];
    float dot = 0.f;
    #pragma unroll
    for (int c = 0; c < 2; ++c) {
      const int kk = l * 2 + c;
      const size_t qc = ((size_t)(row >> 4) * 8 + kk) * 64 + (row & 15);
      const size_t ac = ((size_t)(lab >> 4) * 8 + kk) * 64 + (lab & 15);
      #pragma unroll
      for (int qd = 0; qd < 4; ++qd) {
        bf16x8 qv = qb[qc + qd * 16];
        bf16x8 av = bb[ac + qd * 16];
        #pragma unroll
        for (int j = 0; j < 8; ++j) dot = fmaf(bf2f(qv[j]), bf2f(av[j]), dot);
      }
    }
    dot += __shfl_xor(dot, 1);
    dot += __shfl_xor(dot, 2);
    if (l == 0) slabws[row] = fmaf(dot, 2.f * L2E, cb[lab]);
  }
}

// ---------------------------------------------------------------------------
// merge: 16384 rows, one thread each; 4-way chunk merge + loss/prec1 finalize.
// ---------------------------------------------------------------------------
__global__ __launch_bounds__(256) void proto_merge(
    const float* __restrict__ partm, const float* __restrict__ parts,
    const int* __restrict__ partbi, const float* __restrict__ slabws,
    const int* __restrict__ label,
    float* __restrict__ accum, int* __restrict__ fincount,
    float* __restrict__ out) {
  const int tid = threadIdx.x, row = blockIdx.x * 256 + tid;
  const int wid = tid >> 6;

  float mm = partm[row], sv = parts[row];
  int   b  = partbi[row];
  #pragma unroll
  for (int c = 1; c < 4; ++c) {                      // chunks in ascending cols
    float om = partm[c * NROW + row], os = parts[c * NROW + row];
    int   oi = partbi[c * NROW + row];
    float nm = fmaxf(mm, om);
    sv = sv * exp2f(mm - nm) + os * exp2f(om - nm);
    bool better = (om > mm) || (om == mm && oi < b);
    b = better ? oi : b;
    mm = nm;
  }

  const int lb = label[row >> 3];
  float loss = LN2 * (mm + log2f(sv) - slabws[row]);
  float corr = (b == lb) ? 1.f : 0.f;

  #pragma unroll
  for (int mask = 32; mask; mask >>= 1) {
    loss += __shfl_xor(loss, mask);
    corr += __shfl_xor(corr, mask);
  }
  __shared__ float red[2][4];
  if ((tid & 63) == 0) { red[0][wid] = loss; red[1][wid] = corr; }
  __syncthreads();
  if (tid == 0) {
    float L = red[0][0] + red[0][1] + red[0][2] + red[0][3];
    float C = red[1][0] + red[1][1] + red[1][2] + red[1][3];
    atomicAdd(&accum[0], L);
    atomicAdd(&accum[1], C);
    __threadfence();
    if (atomicAdd(fincount, 1) == (int)gridDim.x - 1) {
      out[0] = atomicAdd(&accum[0], 0.f) / (float)NROW;     // coherent reads
      out[1] = atomicAdd(&accum[1], 0.f) * 100.f / (float)NROW;
    }
  }
}

// ---------------------------------------------------------------------------
extern "C" void kernel_launch(void* const* d_in, const int* in_sizes, int n_in,
                              void* d_out, int out_size, void* d_ws, size_t ws_size,
                              hipStream_t stream) {
  const float* x     = (const float*)d_in[0];
  const int*   label = (const int*)d_in[1];
  float* out = (float*)d_out;

  // ws layout (float-sized slots): [0:2) accum | [2] fincount |
  // [16,16+NCOL) cb | Asw (NCOL*DD ushort) | Qsw (NROW*DD ushort) |
  // partm[4*NROW] | parts[4*NROW] | partbi[4*NROW] | slab[NROW]  (~850 KB)
  float*  W        = (float*)d_ws;
  float*  accum    = W;
  int*    fincount = (int*)(W + 2);
  float*  cb       = W + 16;
  ushort* Asw      = (ushort*)(cb + NCOL);
  ushort* Qsw      = Asw + (size_t)NCOL * DD;
  float*  partm    = (float*)(Qsw + (size_t)NROW * DD);
  float*  parts    = partm + 4 * NROW;
  int*    partbi   = (int*)(parts + 4 * NROW);
  float*  slabws   = (float*)(partbi + 4 * NROW);

  hipLaunchKernelGGL(proto_prep, dim3(NEP / 4), dim3(256), 0, stream,
                     x, cb, Asw, Qsw, accum, fincount);
  hipLaunchKernelGGL(proto_main, dim3(256), dim3(1024), 0, stream,
                     Qsw, Asw, cb, label, partm, parts, partbi, slabws);
  hipLaunchKernelGGL(proto_merge, dim3(NROW / 256), dim3(256), 0, stream,
                     partm, parts, partbi, slabws, label, accum, fincount, out);
}

// Round 11
// 123.878 us; speedup vs baseline: 1.0132x; 1.0132x over previous
//
#include <hip/hip_runtime.h>
#include <math.h>

#define EPS  1e-6f
#define DD   256
#define NSUP 5
#define NQ   8
#define SEQ  13
#define L2E  1.44269504088896f
#define LN2  0.693147180559945f
#define NEP  2048            // episodes
#define NROW 16384           // NEP*NQ query rows
#define NCOL 2048            // anchor columns

typedef short bf16x8 __attribute__((ext_vector_type(8)));
typedef unsigned short u16x4 __attribute__((ext_vector_type(4)));
typedef float f32x4  __attribute__((ext_vector_type(4)));

__device__ __forceinline__ ushort f2bf(float f) {
  union { float f; unsigned u; } v; v.f = f;
  unsigned r = v.u + 0x7FFFu + ((v.u >> 16) & 1u);   // round-to-nearest-even
  return (ushort)(r >> 16);
}
__device__ __forceinline__ float bf2f(short u) {
  union { unsigned u; float f; } v; v.u = ((unsigned)(unsigned short)u) << 16;
  return v.f;
}

// ---------------------------------------------------------------------------
// prep (r8-proven, unchanged): anchors/queries in MFMA-fragment-SWIZZLED order;
// element (c,d) -> ushort idx (((c>>4)*8+(d>>5))*64 + ((d>>3)&3)*16 + (c&15))*8+(d&7).
// cb[c] = -log2(e)*(sum(a^2) - 2*eps*sum(a)); row-constant cq cancels.
// ---------------------------------------------------------------------------
__global__ __launch_bounds__(256) void proto_prep(
    const float* __restrict__ x, float* __restrict__ cb,
    ushort* __restrict__ Asw, ushort* __restrict__ Qsw,
    float* __restrict__ accum, int* __restrict__ fincount) {
  const int tid = threadIdx.x, g = tid >> 6, l = tid & 63;
  const int n = blockIdx.x * 4 + g;
  if (blockIdx.x == 0 && tid == 0) { accum[0] = 0.f; accum[1] = 0.f; fincount[0] = 0; }

  const float4* xr4 = (const float4*)(x + (size_t)n * SEQ * DD);

  const int d0   = l * 4;
  const int kk   = d0 >> 5, quad = (d0 >> 3) & 3, j = d0 & 7;   // j in {0,4}
  const size_t chunk_d = (size_t)kk * 64 + (size_t)quad * 16;

  float4 a = {0.f, 0.f, 0.f, 0.f};
  #pragma unroll
  for (int s = 0; s < NSUP; ++s) {
    float4 v = xr4[s * 64 + l];
    a.x += v.x; a.y += v.y; a.z += v.z; a.w += v.w;
  }
  a.x *= 0.2f; a.y *= 0.2f; a.z *= 0.2f; a.w *= 0.2f;
  {
    const size_t idx = (((size_t)(n >> 4) * 8) * 64 + chunk_d + (n & 15)) * 8 + j;
    u16x4 o = {f2bf(a.x), f2bf(a.y), f2bf(a.z), f2bf(a.w)};
    *(u16x4*)(Asw + idx) = o;
  }
  float s1 = a.x + a.y + a.z + a.w;
  float s2 = a.x * a.x + a.y * a.y + a.z * a.z + a.w * a.w;
  #pragma unroll
  for (int off = 32; off; off >>= 1) {
    s1 += __shfl_xor(s1, off);
    s2 += __shfl_xor(s2, off);
  }
  if (l == 0) cb[n] = -L2E * (s2 - 2.f * EPS * s1);

  #pragma unroll
  for (int s = 0; s < NQ; ++s) {
    float4 q = xr4[(NSUP + s) * 64 + l];
    const int row = n * NQ + s;
    const size_t idx = (((size_t)(row >> 4) * 8) * 64 + chunk_d + (row & 15)) * 8 + j;
    u16x4 o = {f2bf(q.x), f2bf(q.y), f2bf(q.z), f2bf(q.w)};
    *(u16x4*)(Qsw + idx) = o;
  }
}

// ---------------------------------------------------------------------------
// main r23: r22 + XCD-LOCALITY SWIZZLE (single variable). r22's 256x512 tile
// improved per-CU flow (384 KB) but regressed to 52.5 us because blockIdx =
// rb*4+colc put the 4 blocks sharing one A-panel on 4 DIFFERENT XCDs (round-
// robin %8): each re-fetched the 128 KB panel through its own L2 from L3 —
// FETCH_SIZE 8.35 -> 23 MB. Fix: blockIdx = colc*64 + rb. A-siblings
// {rb, 64+rb, 128+rb, 192+rb} are congruent mod 8 -> SAME XCD, co-resident
// (grid 256 = 1 block/CU) -> one L3 fetch per panel. Per-XCD working set:
// 8 A-panels (1 MB) + 4 B-chunks (1 MB) = 2 MB < 4 MB L2: the entire
// steady-state operand feed becomes L2-hits. No arithmetic/order change ->
// absmax 0.0 preserved (swizzle only permutes which CU does which work).
// Structure (r22): 256 rows x 512 cols, 16 waves = 8 rowg x 2 colg,
// af[2][8], 16 steps, 2-deep dbuf, 1 stage-load/wave, sCb broadcast.
// LDS: Bl 32K + sCb 2K + merge 7K = 41 KB. VGPR ~64: no spill.
// MFMA layouts (verified): A m=lane&15,k=quad*8+j ; B n=lane&15,k=quad*8+j ;
// C col=lane&15,row=quad*4+reg.
// ---------------------------------------------------------------------------
__global__ __launch_bounds__(1024, 4) void proto_main(
    const ushort* __restrict__ Qsw, const ushort* __restrict__ Asw,
    const float* __restrict__ cb, const int* __restrict__ label,
    float* __restrict__ partm, float* __restrict__ parts,
    int* __restrict__ partbi, float* __restrict__ slabws) {
  const int tid  = threadIdx.x;
  const int wid  = tid >> 6, lane = tid & 63;
  const int quad = lane >> 4, lcol = lane & 15;
  const int rowg = wid & 7, colg = wid >> 3;        // 8 x 2 wave grid
  const int rb   = blockIdx.x & 63;                 // row-block (256 rows)
  const int colc = blockIdx.x >> 6;                 // col-chunk (512 cols)
  const int r0   = rb * 256;

  const bf16x8* qb = (const bf16x8*)Qsw;
  const bf16x8* bb = (const bf16x8*)Asw;

  __shared__ bf16x8 Bl[2][2][8][64];                 // 32 KiB B staging
  __shared__ float  sCb[512];                        // this chunk's col consts

  if (tid < 512) sCb[tid] = cb[colc * 512 + tid];    // one-time, coalesced

  // resident A fragments: this wave's 32 rows (2 sets) x 8 K-chunks (64 VGPR)
  bf16x8 af[2][8];
  #pragma unroll
  for (int set = 0; set < 2; ++set) {
    const size_t base = ((size_t)(rb * 16 + rowg * 2 + set) * 8) * 64 + lane;
    #pragma unroll
    for (int kk = 0; kk < 8; ++kk) af[set][kk] = qb[base + (size_t)kk * 64];
  }

  float m[2][4], s[2][4];
  int   bi[2][4];
  #pragma unroll
  for (int set = 0; set < 2; ++set)
    #pragma unroll
    for (int i = 0; i < 4; ++i) {
      m[set][i] = -1e30f; s[set][i] = 0.f; bi[set][i] = 0x7fffffff;
    }

  // wave (rowg) stages K-chunk kk=rowg of tile tl into buf b: 1 x
  // global_load_lds width=16 (linear dest: base + lane*16). [G13/T3]
  auto stage = [&](int tl, int b) {
    const int T = colc * 32 + colg * 16 + tl;        // global 16-col tile id
    const ushort* src = Asw + (((size_t)T * 8 + rowg) * 64 + lane) * 8;
    __builtin_amdgcn_global_load_lds(
        (const __attribute__((address_space(1))) void*)src,
        (__attribute__((address_space(3))) void*)&Bl[colg][b][rowg][0],
        16, 0, 0);
  };

  auto compute = [&](int tl, int b) {
    f32x4 c0 = {0.f, 0.f, 0.f, 0.f}, c1 = {0.f, 0.f, 0.f, 0.f};
    #pragma unroll
    for (int kk = 0; kk < 8; ++kk) {
      bf16x8 bf = Bl[colg][b][kk][lane];
      c0 = __builtin_amdgcn_mfma_f32_16x16x32_bf16(af[0][kk], bf, c0, 0, 0, 0);
      c1 = __builtin_amdgcn_mfma_f32_16x16x32_bf16(af[1][kk], bf, c1, 0, 0, 0);
    }
    const int   lcIdx  = (colg * 16 + tl) * 16 + lcol;   // chunk-local col
    const int   colIdx = colc * 512 + lcIdx;             // global col (for bi)
    const float cbv    = sCb[lcIdx];                     // LDS broadcast
    #pragma unroll
    for (int set = 0; set < 2; ++set) {
      #pragma unroll
      for (int i = 0; i < 4; ++i) {
        float cv = set ? c1[i] : c0[i];
        float v2 = fmaf(cv, 2.f * L2E, cbv);         // log2-frame shifted logit
        float dv = v2 - m[set][i];
        bool  gt = dv > 0.f;
        float e  = exp2f(-fabsf(dv));                // single non-unit exp factor
        s[set][i]  = fmaf(s[set][i], gt ? e : 1.f, gt ? 1.f : e);
        m[set][i]  = fmaxf(m[set][i], v2);
        bi[set][i] = gt ? colIdx : bi[set][i];       // strict >: first max wins
      }
    }
  };

  stage(0, 0);
  __syncthreads();                                   // tile 0 + sCb ready

  #pragma unroll 1
  for (int t = 0; t < 16; t += 2) {
    stage(t + 1, 1);                                 // t+1 always < 16
    compute(t, 0);
    __syncthreads();                                 // t+1 staged; buf0 free
    if (t + 2 < 16) stage(t + 2, 0);
    compute(t + 1, 1);
    __syncthreads();                                 // t+2 staged; buf1 free
  }

  // merge across the 16 lanes sharing rows (cols differ)
  #pragma unroll
  for (int mask = 1; mask < 16; mask <<= 1) {
    #pragma unroll
    for (int set = 0; set < 2; ++set)
      #pragma unroll
      for (int i = 0; i < 4; ++i) {
        float om = __shfl_xor(m[set][i], mask);
        float os = __shfl_xor(s[set][i], mask);
        int   oi = __shfl_xor(bi[set][i], mask);
        float nm = fmaxf(m[set][i], om);
        s[set][i] = s[set][i] * exp2f(m[set][i] - nm) + os * exp2f(om - nm);
        bool better = (om > m[set][i]) || (om == m[set][i] && oi < bi[set][i]);
        bi[set][i] = better ? oi : bi[set][i];
        m[set][i]  = nm;
      }
  }

  __shared__ float sm[2][256], ssh[2][256];
  __shared__ int   sbi[2][256];
  if (lcol == 0) {
    #pragma unroll
    for (int set = 0; set < 2; ++set)
      #pragma unroll
      for (int i = 0; i < 4; ++i) {
        int rl = rowg * 32 + set * 16 + quad * 4 + i;
        sm[colg][rl] = m[set][i]; ssh[colg][rl] = s[set][i]; sbi[colg][rl] = bi[set][i];
      }
  }
  __syncthreads();

  // in-block merge over the 2 colg stripes (ascending cols) -> ws partials
  if (tid < 256) {
    float mm = sm[0][tid], sv = ssh[0][tid];
    int   b  = sbi[0][tid];
    {
      float om = sm[1][tid], os = ssh[1][tid];
      int   oi = sbi[1][tid];
      float nm = fmaxf(mm, om);
      sv = sv * exp2f(mm - nm) + os * exp2f(om - nm);
      bool better = (om > mm) || (om == mm && oi < b);
      b = better ? oi : b;
      mm = nm;
    }
    const int row = r0 + tid;
    partm [colc * NROW + row] = mm;
    parts [colc * NROW + row] = sv;
    partbi[colc * NROW + row] = b;
  }

  // label-logit pass (r11-proven 4-lane pattern), colc==0 blocks only:
  // 4 lanes/row x 256 rows = 1024 threads; lane l handles K-chunks {2l,2l+1}.
  if (colc == 0) {
    const int rl = tid >> 2, l = tid & 3;
    const int row = r0 + rl;
    const int lab = label[row >> 3];
    float dot = 0.f;
    #pragma unroll
    for (int c = 0; c < 2; ++c) {
      const int kk = l * 2 + c;
      const size_t qc = ((size_t)(row >> 4) * 8 + kk) * 64 + (row & 15);
      const size_t ac = ((size_t)(lab >> 4) * 8 + kk) * 64 + (lab & 15);
      #pragma unroll
      for (int qd = 0; qd < 4; ++qd) {
        bf16x8 qv = qb[qc + qd * 16];
        bf16x8 av = bb[ac + qd * 16];
        #pragma unroll
        for (int j = 0; j < 8; ++j) dot = fmaf(bf2f(qv[j]), bf2f(av[j]), dot);
      }
    }
    dot += __shfl_xor(dot, 1);
    dot += __shfl_xor(dot, 2);
    if (l == 0) slabws[row] = fmaf(dot, 2.f * L2E, cb[lab]);
  }
}

// ---------------------------------------------------------------------------
// merge: 16384 rows, one thread each; 4-way chunk merge + loss/prec1 finalize.
// ---------------------------------------------------------------------------
__global__ __launch_bounds__(256) void proto_merge(
    const float* __restrict__ partm, const float* __restrict__ parts,
    const int* __restrict__ partbi, const float* __restrict__ slabws,
    const int* __restrict__ label,
    float* __restrict__ accum, int* __restrict__ fincount,
    float* __restrict__ out) {
  const int tid = threadIdx.x, row = blockIdx.x * 256 + tid;
  const int wid = tid >> 6;

  float mm = partm[row], sv = parts[row];
  int   b  = partbi[row];
  #pragma unroll
  for (int c = 1; c < 4; ++c) {                      // chunks in ascending cols
    float om = partm[c * NROW + row], os = parts[c * NROW + row];
    int   oi = partbi[c * NROW + row];
    float nm = fmaxf(mm, om);
    sv = sv * exp2f(mm - nm) + os * exp2f(om - nm);
    bool better = (om > mm) || (om == mm && oi < b);
    b = better ? oi : b;
    mm = nm;
  }

  const int lb = label[row >> 3];
  float loss = LN2 * (mm + log2f(sv) - slabws[row]);
  float corr = (b == lb) ? 1.f : 0.f;

  #pragma unroll
  for (int mask = 32; mask; mask >>= 1) {
    loss += __shfl_xor(loss, mask);
    corr += __shfl_xor(corr, mask);
  }
  __shared__ float red[2][4];
  if ((tid & 63) == 0) { red[0][wid] = loss; red[1][wid] = corr; }
  __syncthreads();
  if (tid == 0) {
    float L = red[0][0] + red[0][1] + red[0][2] + red[0][3];
    float C = red[1][0] + red[1][1] + red[1][2] + red[1][3];
    atomicAdd(&accum[0], L);
    atomicAdd(&accum[1], C);
    __threadfence();
    if (atomicAdd(fincount, 1) == (int)gridDim.x - 1) {
      out[0] = atomicAdd(&accum[0], 0.f) / (float)NROW;     // coherent reads
      out[1] = atomicAdd(&accum[1], 0.f) * 100.f / (float)NROW;
    }
  }
}

// ---------------------------------------------------------------------------
extern "C" void kernel_launch(void* const* d_in, const int* in_sizes, int n_in,
                              void* d_out, int out_size, void* d_ws, size_t ws_size,
                              hipStream_t stream) {
  const float* x     = (const float*)d_in[0];
  const int*   label = (const int*)d_in[1];
  float* out = (float*)d_out;

  // ws layout (float-sized slots): [0:2) accum | [2] fincount |
  // [16,16+NCOL) cb | Asw (NCOL*DD ushort) | Qsw (NROW*DD ushort) |
  // partm[4*NROW] | parts[4*NROW] | partbi[4*NROW] | slab[NROW]  (~850 KB)
  float*  W        = (float*)d_ws;
  float*  accum    = W;
  int*    fincount = (int*)(W + 2);
  float*  cb       = W + 16;
  ushort* Asw      = (ushort*)(cb + NCOL);
  ushort* Qsw      = Asw + (size_t)NCOL * DD;
  float*  partm    = (float*)(Qsw + (size_t)NROW * DD);
  float*  parts    = partm + 4 * NROW;
  int*    partbi   = (int*)(parts + 4 * NROW);
  float*  slabws   = (float*)(partbi + 4 * NROW);

  hipLaunchKernelGGL(proto_prep, dim3(NEP / 4), dim3(256), 0, stream,
                     x, cb, Asw, Qsw, accum, fincount);
  hipLaunchKernelGGL(proto_main, dim3(256), dim3(1024), 0, stream,
                     Qsw, Asw, cb, label, partm, parts, partbi, slabws);
  hipLaunchKernelGGL(proto_merge, dim3(NROW / 256), dim3(256), 0, stream,
                     partm, parts, partbi, slabws, label, accum, fincount, out);
}

// Round 12
// 121.154 us; speedup vs baseline: 1.0360x; 1.0225x over previous
//
#include <hip/hip_runtime.h>
#include <math.h>

#define EPS  1e-6f
#define DD   256
#define NSUP 5
#define NQ   8
#define SEQ  13
#define L2E  1.44269504088896f
#define LN2  0.693147180559945f
#define NEP  2048            // episodes
#define NROW 16384           // NEP*NQ query rows
#define NCOL 2048            // anchor columns

typedef short bf16x8 __attribute__((ext_vector_type(8)));
typedef unsigned short u16x4 __attribute__((ext_vector_type(4)));
typedef float f32x4  __attribute__((ext_vector_type(4)));

__device__ __forceinline__ ushort f2bf(float f) {
  union { float f; unsigned u; } v; v.f = f;
  unsigned r = v.u + 0x7FFFu + ((v.u >> 16) & 1u);   // round-to-nearest-even
  return (ushort)(r >> 16);
}
__device__ __forceinline__ float bf2f(short u) {
  union { unsigned u; float f; } v; v.u = ((unsigned)(unsigned short)u) << 16;
  return v.f;
}

// ---------------------------------------------------------------------------
// prep (r8-proven, unchanged): anchors/queries in MFMA-fragment-SWIZZLED order;
// element (c,d) -> ushort idx (((c>>4)*8+(d>>5))*64 + ((d>>3)&3)*16 + (c&15))*8+(d&7).
// cb[c] = -log2(e)*(sum(a^2) - 2*eps*sum(a)); row-constant cq cancels.
// ---------------------------------------------------------------------------
__global__ __launch_bounds__(256) void proto_prep(
    const float* __restrict__ x, float* __restrict__ cb,
    ushort* __restrict__ Asw, ushort* __restrict__ Qsw,
    float* __restrict__ accum, int* __restrict__ fincount) {
  const int tid = threadIdx.x, g = tid >> 6, l = tid & 63;
  const int n = blockIdx.x * 4 + g;
  if (blockIdx.x == 0 && tid == 0) { accum[0] = 0.f; accum[1] = 0.f; fincount[0] = 0; }

  const float4* xr4 = (const float4*)(x + (size_t)n * SEQ * DD);

  const int d0   = l * 4;
  const int kk   = d0 >> 5, quad = (d0 >> 3) & 3, j = d0 & 7;   // j in {0,4}
  const size_t chunk_d = (size_t)kk * 64 + (size_t)quad * 16;

  float4 a = {0.f, 0.f, 0.f, 0.f};
  #pragma unroll
  for (int s = 0; s < NSUP; ++s) {
    float4 v = xr4[s * 64 + l];
    a.x += v.x; a.y += v.y; a.z += v.z; a.w += v.w;
  }
  a.x *= 0.2f; a.y *= 0.2f; a.z *= 0.2f; a.w *= 0.2f;
  {
    const size_t idx = (((size_t)(n >> 4) * 8) * 64 + chunk_d + (n & 15)) * 8 + j;
    u16x4 o = {f2bf(a.x), f2bf(a.y), f2bf(a.z), f2bf(a.w)};
    *(u16x4*)(Asw + idx) = o;
  }
  float s1 = a.x + a.y + a.z + a.w;
  float s2 = a.x * a.x + a.y * a.y + a.z * a.z + a.w * a.w;
  #pragma unroll
  for (int off = 32; off; off >>= 1) {
    s1 += __shfl_xor(s1, off);
    s2 += __shfl_xor(s2, off);
  }
  if (l == 0) cb[n] = -L2E * (s2 - 2.f * EPS * s1);

  #pragma unroll
  for (int s = 0; s < NQ; ++s) {
    float4 q = xr4[(NSUP + s) * 64 + l];
    const int row = n * NQ + s;
    const size_t idx = (((size_t)(row >> 4) * 8) * 64 + chunk_d + (row & 15)) * 8 + j;
    u16x4 o = {f2bf(q.x), f2bf(q.y), f2bf(q.z), f2bf(q.w)};
    *(u16x4*)(Qsw + idx) = o;
  }
}

// ---------------------------------------------------------------------------
// main r24: LDS-READ HALVING via sets=4. r23 (45.9 us, FETCH healthy after
// the XCD swizzle) showed flow is no longer binding; the largest modeled
// interval component is the LDS B-read stream: LDS-read bytes/CU =
// rows*cols*32/sets = 2 MB at sets=2 (~1540 cyc of the measured 3.3k-cyc
// interval). sets=4 halves it to 1 MB. af[4][8]=128 VGPR cannot fit a
// 16-wave block (4 waves/SIMD caps VGPR at 128; r13/r14 proved (512,2)
// won't unlock 256), so: block = 512 threads (8 waves = 4 rowg x 2 colg),
// 1 block/CU, __launch_bounds__(512,1) — r12's (256,1) proved min-occ-1
// lets the allocator exceed 128 (it took 148). Live set ~210 VGPR -> 2
// waves/SIMD. Per B-read feeds 32 MFMA (4 independent chains, r12-style
// ILP). Tile/swizzle/merge identical to r23: 256 rows x 512 cols,
// rb = blk&63, colc = blk>>6; 16 steps, 2-deep dbuf, 2 stage-loads/wave
// (r21's proven pattern), sCb broadcast; partials + 4-way merge kernel.
// GATES: VGPR must be ~200-240 (128 => allocator capped, test void);
// WRITE_SIZE ~850 KB (partials only; more => spill).
// LDS: Bl 32K + sCb 2K + sm/ssh/sbi 6K = 40 KB.
// MFMA layouts (verified): A m=lane&15,k=quad*8+j ; B n=lane&15,k=quad*8+j ;
// C col=lane&15,row=quad*4+reg.
// ---------------------------------------------------------------------------
__global__ __launch_bounds__(512, 1) void proto_main(
    const ushort* __restrict__ Qsw, const ushort* __restrict__ Asw,
    const float* __restrict__ cb, const int* __restrict__ label,
    float* __restrict__ partm, float* __restrict__ parts,
    int* __restrict__ partbi, float* __restrict__ slabws) {
  const int tid  = threadIdx.x;
  const int wid  = tid >> 6, lane = tid & 63;
  const int quad = lane >> 4, lcol = lane & 15;
  const int rowg = wid & 3, colg = wid >> 2;        // 4 x 2 wave grid
  const int rb   = blockIdx.x & 63;                 // row-block (256 rows)
  const int colc = blockIdx.x >> 6;                 // col-chunk (512 cols)
  const int r0   = rb * 256;

  const bf16x8* qb = (const bf16x8*)Qsw;
  const bf16x8* bb = (const bf16x8*)Asw;

  __shared__ bf16x8 Bl[2][2][8][64];                 // 32 KiB B staging
  __shared__ float  sCb[512];                        // this chunk's col consts

  sCb[tid] = cb[colc * 512 + tid];                   // one-time, coalesced

  // resident A fragments: this wave's 64 rows (4 sets) x 8 K-chunks (128 VGPR)
  bf16x8 af[4][8];
  #pragma unroll
  for (int set = 0; set < 4; ++set) {
    const size_t base = ((size_t)(rb * 16 + rowg * 4 + set) * 8) * 64 + lane;
    #pragma unroll
    for (int kk = 0; kk < 8; ++kk) af[set][kk] = qb[base + (size_t)kk * 64];
  }

  float m[4][4], s[4][4];
  int   bi[4][4];
  #pragma unroll
  for (int set = 0; set < 4; ++set)
    #pragma unroll
    for (int i = 0; i < 4; ++i) {
      m[set][i] = -1e30f; s[set][i] = 0.f; bi[set][i] = 0x7fffffff;
    }

  // wave (rowg) stages K-chunks {2*rowg, 2*rowg+1} of its group's tile tl
  // into buf b: 2 x global_load_lds width=16 (linear dest). [G13/T3]
  const int kk0 = rowg * 2;
  auto stage = [&](int tl, int b) {
    const int T = colc * 32 + colg * 16 + tl;        // global 16-col tile id
    #pragma unroll
    for (int k2 = 0; k2 < 2; ++k2) {
      const int kk = kk0 + k2;
      const ushort* src = Asw + (((size_t)T * 8 + kk) * 64 + lane) * 8;
      __builtin_amdgcn_global_load_lds(
          (const __attribute__((address_space(1))) void*)src,
          (__attribute__((address_space(3))) void*)&Bl[colg][b][kk][0],
          16, 0, 0);
    }
  };

  auto compute = [&](int tl, int b) {
    f32x4 c0 = {0.f, 0.f, 0.f, 0.f}, c1 = {0.f, 0.f, 0.f, 0.f};
    f32x4 c2 = {0.f, 0.f, 0.f, 0.f}, c3 = {0.f, 0.f, 0.f, 0.f};
    #pragma unroll
    for (int kk = 0; kk < 8; ++kk) {
      bf16x8 bf = Bl[colg][b][kk][lane];
      c0 = __builtin_amdgcn_mfma_f32_16x16x32_bf16(af[0][kk], bf, c0, 0, 0, 0);
      c1 = __builtin_amdgcn_mfma_f32_16x16x32_bf16(af[1][kk], bf, c1, 0, 0, 0);
      c2 = __builtin_amdgcn_mfma_f32_16x16x32_bf16(af[2][kk], bf, c2, 0, 0, 0);
      c3 = __builtin_amdgcn_mfma_f32_16x16x32_bf16(af[3][kk], bf, c3, 0, 0, 0);
    }
    const int   lcIdx  = (colg * 16 + tl) * 16 + lcol;   // chunk-local col
    const int   colIdx = colc * 512 + lcIdx;             // global col (for bi)
    const float cbv    = sCb[lcIdx];                     // LDS broadcast
    #pragma unroll
    for (int set = 0; set < 4; ++set) {
      #pragma unroll
      for (int i = 0; i < 4; ++i) {
        float cv = (set == 0) ? c0[i] : (set == 1) ? c1[i]
                 : (set == 2) ? c2[i] : c3[i];
        float v2 = fmaf(cv, 2.f * L2E, cbv);         // log2-frame shifted logit
        float dv = v2 - m[set][i];
        bool  gt = dv > 0.f;
        float e  = exp2f(-fabsf(dv));                // single non-unit exp factor
        s[set][i]  = fmaf(s[set][i], gt ? e : 1.f, gt ? 1.f : e);
        m[set][i]  = fmaxf(m[set][i], v2);
        bi[set][i] = gt ? colIdx : bi[set][i];       // strict >: first max wins
      }
    }
  };

  stage(0, 0);
  __syncthreads();                                   // tile 0 + sCb ready

  #pragma unroll 1
  for (int t = 0; t < 16; t += 2) {
    stage(t + 1, 1);                                 // t+1 always < 16
    compute(t, 0);
    __syncthreads();                                 // t+1 staged; buf0 free
    if (t + 2 < 16) stage(t + 2, 0);
    compute(t + 1, 1);
    __syncthreads();                                 // t+2 staged; buf1 free
  }

  // merge across the 16 lanes sharing rows (cols differ)
  #pragma unroll
  for (int mask = 1; mask < 16; mask <<= 1) {
    #pragma unroll
    for (int set = 0; set < 4; ++set)
      #pragma unroll
      for (int i = 0; i < 4; ++i) {
        float om = __shfl_xor(m[set][i], mask);
        float os = __shfl_xor(s[set][i], mask);
        int   oi = __shfl_xor(bi[set][i], mask);
        float nm = fmaxf(m[set][i], om);
        s[set][i] = s[set][i] * exp2f(m[set][i] - nm) + os * exp2f(om - nm);
        bool better = (om > m[set][i]) || (om == m[set][i] && oi < bi[set][i]);
        bi[set][i] = better ? oi : bi[set][i];
        m[set][i]  = nm;
      }
  }

  __shared__ float sm[2][256], ssh[2][256];
  __shared__ int   sbi[2][256];
  if (lcol == 0) {
    #pragma unroll
    for (int set = 0; set < 4; ++set)
      #pragma unroll
      for (int i = 0; i < 4; ++i) {
        int rl = rowg * 64 + set * 16 + quad * 4 + i;
        sm[colg][rl] = m[set][i]; ssh[colg][rl] = s[set][i]; sbi[colg][rl] = bi[set][i];
      }
  }
  __syncthreads();

  // in-block merge over the 2 colg stripes (ascending cols) -> ws partials
  if (tid < 256) {
    float mm = sm[0][tid], sv = ssh[0][tid];
    int   b  = sbi[0][tid];
    {
      float om = sm[1][tid], os = ssh[1][tid];
      int   oi = sbi[1][tid];
      float nm = fmaxf(mm, om);
      sv = sv * exp2f(mm - nm) + os * exp2f(om - nm);
      bool better = (om > mm) || (om == mm && oi < b);
      b = better ? oi : b;
      mm = nm;
    }
    const int row = r0 + tid;
    partm [colc * NROW + row] = mm;
    parts [colc * NROW + row] = sv;
    partbi[colc * NROW + row] = b;
  }

  // label-logit pass (r11-proven dot), colc==0 blocks only: 2 lanes/row x
  // 256 rows = 512 threads; lane l handles K-chunks 4l..4l+3.
  if (colc == 0) {
    const int rl = tid >> 1, l = tid & 1;
    const int row = r0 + rl;
    const int lab = label[row >> 3];
    float dot = 0.f;
    #pragma unroll
    for (int c = 0; c < 4; ++c) {
      const int kk = l * 4 + c;
      const size_t qc = ((size_t)(row >> 4) * 8 + kk) * 64 + (row & 15);
      const size_t ac = ((size_t)(lab >> 4) * 8 + kk) * 64 + (lab & 15);
      #pragma unroll
      for (int qd = 0; qd < 4; ++qd) {
        bf16x8 qv = qb[qc + qd * 16];
        bf16x8 av = bb[ac + qd * 16];
        #pragma unroll
        for (int j = 0; j < 8; ++j) dot = fmaf(bf2f(qv[j]), bf2f(av[j]), dot);
      }
    }
    dot += __shfl_xor(dot, 1);
    if (l == 0) slabws[row] = fmaf(dot, 2.f * L2E, cb[lab]);
  }
}

// ---------------------------------------------------------------------------
// merge: 16384 rows, one thread each; 4-way chunk merge + loss/prec1 finalize.
// ---------------------------------------------------------------------------
__global__ __launch_bounds__(256) void proto_merge(
    const float* __restrict__ partm, const float* __restrict__ parts,
    const int* __restrict__ partbi, const float* __restrict__ slabws,
    const int* __restrict__ label,
    float* __restrict__ accum, int* __restrict__ fincount,
    float* __restrict__ out) {
  const int tid = threadIdx.x, row = blockIdx.x * 256 + tid;
  const int wid = tid >> 6;

  float mm = partm[row], sv = parts[row];
  int   b  = partbi[row];
  #pragma unroll
  for (int c = 1; c < 4; ++c) {                      // chunks in ascending cols
    float om = partm[c * NROW + row], os = parts[c * NROW + row];
    int   oi = partbi[c * NROW + row];
    float nm = fmaxf(mm, om);
    sv = sv * exp2f(mm - nm) + os * exp2f(om - nm);
    bool better = (om > mm) || (om == mm && oi < b);
    b = better ? oi : b;
    mm = nm;
  }

  const int lb = label[row >> 3];
  float loss = LN2 * (mm + log2f(sv) - slabws[row]);
  float corr = (b == lb) ? 1.f : 0.f;

  #pragma unroll
  for (int mask = 32; mask; mask >>= 1) {
    loss += __shfl_xor(loss, mask);
    corr += __shfl_xor(corr, mask);
  }
  __shared__ float red[2][4];
  if ((tid & 63) == 0) { red[0][wid] = loss; red[1][wid] = corr; }
  __syncthreads();
  if (tid == 0) {
    float L = red[0][0] + red[0][1] + red[0][2] + red[0][3];
    float C = red[1][0] + red[1][1] + red[1][2] + red[1][3];
    atomicAdd(&accum[0], L);
    atomicAdd(&accum[1], C);
    __threadfence();
    if (atomicAdd(fincount, 1) == (int)gridDim.x - 1) {
      out[0] = atomicAdd(&accum[0], 0.f) / (float)NROW;     // coherent reads
      out[1] = atomicAdd(&accum[1], 0.f) * 100.f / (float)NROW;
    }
  }
}

// ---------------------------------------------------------------------------
extern "C" void kernel_launch(void* const* d_in, const int* in_sizes, int n_in,
                              void* d_out, int out_size, void* d_ws, size_t ws_size,
                              hipStream_t stream) {
  const float* x     = (const float*)d_in[0];
  const int*   label = (const int*)d_in[1];
  float* out = (float*)d_out;

  // ws layout (float-sized slots): [0:2) accum | [2] fincount |
  // [16,16+NCOL) cb | Asw (NCOL*DD ushort) | Qsw (NROW*DD ushort) |
  // partm[4*NROW] | parts[4*NROW] | partbi[4*NROW] | slab[NROW]  (~850 KB)
  float*  W        = (float*)d_ws;
  float*  accum    = W;
  int*    fincount = (int*)(W + 2);
  float*  cb       = W + 16;
  ushort* Asw      = (ushort*)(cb + NCOL);
  ushort* Qsw      = Asw + (size_t)NCOL * DD;
  float*  partm    = (float*)(Qsw + (size_t)NROW * DD);
  float*  parts    = partm + 4 * NROW;
  int*    partbi   = (int*)(parts + 4 * NROW);
  float*  slabws   = (float*)(partbi + 4 * NROW);

  hipLaunchKernelGGL(proto_prep, dim3(NEP / 4), dim3(256), 0, stream,
                     x, cb, Asw, Qsw, accum, fincount);
  hipLaunchKernelGGL(proto_main, dim3(256), dim3(512), 0, stream,
                     Qsw, Asw, cb, label, partm, parts, partbi, slabws);
  hipLaunchKernelGGL(proto_merge, dim3(NROW / 256), dim3(256), 0, stream,
                     partm, parts, partbi, slabws, label, accum, fincount, out);
}

// Round 13
// 120.797 us; speedup vs baseline: 1.0391x; 1.0030x over previous
//
#include <hip/hip_runtime.h>
#include <math.h>

#define EPS  1e-6f
#define DD   256
#define NSUP 5
#define NQ   8
#define SEQ  13
#define L2E  1.44269504088896f
#define LN2  0.693147180559945f
#define NEP  2048            // episodes
#define NROW 16384           // NEP*NQ query rows
#define NCOL 2048            // anchor columns

typedef short bf16x8 __attribute__((ext_vector_type(8)));
typedef unsigned short u16x4 __attribute__((ext_vector_type(4)));
typedef float f32x4  __attribute__((ext_vector_type(4)));

__device__ __forceinline__ ushort f2bf(float f) {
  union { float f; unsigned u; } v; v.f = f;
  unsigned r = v.u + 0x7FFFu + ((v.u >> 16) & 1u);   // round-to-nearest-even
  return (ushort)(r >> 16);
}
__device__ __forceinline__ float bf2f(short u) {
  union { unsigned u; float f; } v; v.u = ((unsigned)(unsigned short)u) << 16;
  return v.f;
}

// ---------------------------------------------------------------------------
// prep (r8-proven, unchanged): anchors/queries in MFMA-fragment-SWIZZLED order;
// element (c,d) -> ushort idx (((c>>4)*8+(d>>5))*64 + ((d>>3)&3)*16 + (c&15))*8+(d&7).
// cb[c] = -log2(e)*(sum(a^2) - 2*eps*sum(a)); row-constant cq cancels.
// ---------------------------------------------------------------------------
__global__ __launch_bounds__(256) void proto_prep(
    const float* __restrict__ x, float* __restrict__ cb,
    ushort* __restrict__ Asw, ushort* __restrict__ Qsw,
    float* __restrict__ accum, int* __restrict__ fincount) {
  const int tid = threadIdx.x, g = tid >> 6, l = tid & 63;
  const int n = blockIdx.x * 4 + g;
  if (blockIdx.x == 0 && tid == 0) { accum[0] = 0.f; accum[1] = 0.f; fincount[0] = 0; }

  const float4* xr4 = (const float4*)(x + (size_t)n * SEQ * DD);

  const int d0   = l * 4;
  const int kk   = d0 >> 5, quad = (d0 >> 3) & 3, j = d0 & 7;   // j in {0,4}
  const size_t chunk_d = (size_t)kk * 64 + (size_t)quad * 16;

  float4 a = {0.f, 0.f, 0.f, 0.f};
  #pragma unroll
  for (int s = 0; s < NSUP; ++s) {
    float4 v = xr4[s * 64 + l];
    a.x += v.x; a.y += v.y; a.z += v.z; a.w += v.w;
  }
  a.x *= 0.2f; a.y *= 0.2f; a.z *= 0.2f; a.w *= 0.2f;
  {
    const size_t idx = (((size_t)(n >> 4) * 8) * 64 + chunk_d + (n & 15)) * 8 + j;
    u16x4 o = {f2bf(a.x), f2bf(a.y), f2bf(a.z), f2bf(a.w)};
    *(u16x4*)(Asw + idx) = o;
  }
  float s1 = a.x + a.y + a.z + a.w;
  float s2 = a.x * a.x + a.y * a.y + a.z * a.z + a.w * a.w;
  #pragma unroll
  for (int off = 32; off; off >>= 1) {
    s1 += __shfl_xor(s1, off);
    s2 += __shfl_xor(s2, off);
  }
  if (l == 0) cb[n] = -L2E * (s2 - 2.f * EPS * s1);

  #pragma unroll
  for (int s = 0; s < NQ; ++s) {
    float4 q = xr4[(NSUP + s) * 64 + l];
    const int row = n * NQ + s;
    const size_t idx = (((size_t)(row >> 4) * 8) * 64 + chunk_d + (row & 15)) * 8 + j;
    u16x4 o = {f2bf(q.x), f2bf(q.y), f2bf(q.z), f2bf(q.w)};
    *(u16x4*)(Qsw + idx) = o;
  }
}

// ---------------------------------------------------------------------------
// main r25: SPLIT BARRIER DOMAIN (2 blocks/CU). r24 = 43.6 us (best) but the
// interval cost (~6.1k cyc vs ~1.5k modeled issue) survived every CU-local
// and flow fix. Remaining invariant: ONE barrier domain per CU — the whole
// CU serializes on each step's __syncthreads + staging drain, with nothing
// to fill the stall. This round: block = 256 thr (4 waves = 4 rowg), tile
// 256 rows x 256 cols, grid 512 = 64 rb x 8 colc, 2 blocks/CU
// (__launch_bounds__(256,2): 2 waves/EU = 2 blocks/CU at 4-wave blocks).
// When block A stalls at its barrier, block B keeps issuing. Same per-CU
// flow (A 256K + B 256K = 512 KB), same sets=4 wave inner loop, same XCD
// swizzle (blk = colc*64+rb => blk ≡ rb mod 8 -> A-siblings co-XCD; per-XCD
// set: 16 A-panels 2MB + B 512KB < 4MB L2). With 1 colg group each row
// belongs to ONE wave: lane-merge then DIRECT partials write — no LDS merge
// arrays, no post-loop __syncthreads. 8-way chunk merge in proto_merge.
// LDS/block: Bl 16K + sCb 1K = 17 KB (2 blocks -> 34 KB/CU). VGPR ~120
// (+af in AGPRs as r24). GATES: WRITE ~1.6 MB (partials), FETCH ~8.4 MB.
// MFMA layouts (verified): A m=lane&15,k=quad*8+j ; B n=lane&15,k=quad*8+j ;
// C col=lane&15,row=quad*4+reg.
// ---------------------------------------------------------------------------
__global__ __launch_bounds__(256, 2) void proto_main(
    const ushort* __restrict__ Qsw, const ushort* __restrict__ Asw,
    const float* __restrict__ cb, const int* __restrict__ label,
    float* __restrict__ partm, float* __restrict__ parts,
    int* __restrict__ partbi, float* __restrict__ slabws) {
  const int tid  = threadIdx.x;
  const int rowg = tid >> 6, lane = tid & 63;
  const int quad = lane >> 4, lcol = lane & 15;
  const int rb   = blockIdx.x & 63;                 // row-block (256 rows)
  const int colc = blockIdx.x >> 6;                 // col-chunk (256 cols, 0..7)
  const int r0   = rb * 256;

  const bf16x8* qb = (const bf16x8*)Qsw;
  const bf16x8* bb = (const bf16x8*)Asw;

  __shared__ bf16x8 Bl[2][8][64];                    // 16 KiB B staging
  __shared__ float  sCb[256];                        // this chunk's col consts

  sCb[tid] = cb[colc * 256 + tid];                   // one-time, coalesced

  // resident A fragments: this wave's 64 rows (4 sets) x 8 K-chunks
  // (128 regs; lands in AGPRs per r24 — legal MFMA A-source on gfx950)
  bf16x8 af[4][8];
  #pragma unroll
  for (int set = 0; set < 4; ++set) {
    const size_t base = ((size_t)(rb * 16 + rowg * 4 + set) * 8) * 64 + lane;
    #pragma unroll
    for (int kk = 0; kk < 8; ++kk) af[set][kk] = qb[base + (size_t)kk * 64];
  }

  float m[4][4], s[4][4];
  int   bi[4][4];
  #pragma unroll
  for (int set = 0; set < 4; ++set)
    #pragma unroll
    for (int i = 0; i < 4; ++i) {
      m[set][i] = -1e30f; s[set][i] = 0.f; bi[set][i] = 0x7fffffff;
    }

  // wave (rowg) stages K-chunks {2*rowg, 2*rowg+1} of tile tl into buf b:
  // 2 x global_load_lds width=16 (linear dest). [G13/T3]
  const int kk0 = rowg * 2;
  auto stage = [&](int tl, int b) {
    const int T = colc * 16 + tl;                    // global 16-col tile id
    #pragma unroll
    for (int k2 = 0; k2 < 2; ++k2) {
      const int kk = kk0 + k2;
      const ushort* src = Asw + (((size_t)T * 8 + kk) * 64 + lane) * 8;
      __builtin_amdgcn_global_load_lds(
          (const __attribute__((address_space(1))) void*)src,
          (__attribute__((address_space(3))) void*)&Bl[b][kk][0],
          16, 0, 0);
    }
  };

  auto compute = [&](int tl, int b) {
    f32x4 c0 = {0.f, 0.f, 0.f, 0.f}, c1 = {0.f, 0.f, 0.f, 0.f};
    f32x4 c2 = {0.f, 0.f, 0.f, 0.f}, c3 = {0.f, 0.f, 0.f, 0.f};
    #pragma unroll
    for (int kk = 0; kk < 8; ++kk) {
      bf16x8 bf = Bl[b][kk][lane];
      c0 = __builtin_amdgcn_mfma_f32_16x16x32_bf16(af[0][kk], bf, c0, 0, 0, 0);
      c1 = __builtin_amdgcn_mfma_f32_16x16x32_bf16(af[1][kk], bf, c1, 0, 0, 0);
      c2 = __builtin_amdgcn_mfma_f32_16x16x32_bf16(af[2][kk], bf, c2, 0, 0, 0);
      c3 = __builtin_amdgcn_mfma_f32_16x16x32_bf16(af[3][kk], bf, c3, 0, 0, 0);
    }
    const int   lcIdx  = tl * 16 + lcol;             // chunk-local col
    const int   colIdx = colc * 256 + lcIdx;         // global col (for bi)
    const float cbv    = sCb[lcIdx];                 // LDS broadcast
    #pragma unroll
    for (int set = 0; set < 4; ++set) {
      #pragma unroll
      for (int i = 0; i < 4; ++i) {
        float cv = (set == 0) ? c0[i] : (set == 1) ? c1[i]
                 : (set == 2) ? c2[i] : c3[i];
        float v2 = fmaf(cv, 2.f * L2E, cbv);         // log2-frame shifted logit
        float dv = v2 - m[set][i];
        bool  gt = dv > 0.f;
        float e  = exp2f(-fabsf(dv));                // single non-unit exp factor
        s[set][i]  = fmaf(s[set][i], gt ? e : 1.f, gt ? 1.f : e);
        m[set][i]  = fmaxf(m[set][i], v2);
        bi[set][i] = gt ? colIdx : bi[set][i];       // strict >: first max wins
      }
    }
  };

  stage(0, 0);
  __syncthreads();                                   // tile 0 + sCb ready

  #pragma unroll 1
  for (int t = 0; t < 16; t += 2) {
    stage(t + 1, 1);                                 // t+1 always < 16
    compute(t, 0);
    __syncthreads();                                 // t+1 staged; buf0 free
    if (t + 2 < 16) stage(t + 2, 0);
    compute(t + 1, 1);
    __syncthreads();                                 // t+2 staged; buf1 free
  }

  // merge across the 16 lanes sharing rows (cols differ); rows are unique
  // to this wave -> lcol==0 lanes then hold the final per-row partials.
  #pragma unroll
  for (int mask = 1; mask < 16; mask <<= 1) {
    #pragma unroll
    for (int set = 0; set < 4; ++set)
      #pragma unroll
      for (int i = 0; i < 4; ++i) {
        float om = __shfl_xor(m[set][i], mask);
        float os = __shfl_xor(s[set][i], mask);
        int   oi = __shfl_xor(bi[set][i], mask);
        float nm = fmaxf(m[set][i], om);
        s[set][i] = s[set][i] * exp2f(m[set][i] - nm) + os * exp2f(om - nm);
        bool better = (om > m[set][i]) || (om == m[set][i] && oi < bi[set][i]);
        bi[set][i] = better ? oi : bi[set][i];
        m[set][i]  = nm;
      }
  }

  if (lcol == 0) {                                   // direct partials write
    #pragma unroll
    for (int set = 0; set < 4; ++set)
      #pragma unroll
      for (int i = 0; i < 4; ++i) {
        const int row = r0 + rowg * 64 + set * 16 + quad * 4 + i;
        partm [colc * NROW + row] = m[set][i];
        parts [colc * NROW + row] = s[set][i];
        partbi[colc * NROW + row] = bi[set][i];
      }
  }

  // label-logit pass (r11-proven dot), colc==0 blocks only: 1 thread/row,
  // 256 rows = 256 threads; full 8-chunk dot, same rounding as MFMA path.
  if (colc == 0) {
    const int row = r0 + tid;
    const int lab = label[row >> 3];
    float dot = 0.f;
    #pragma unroll
    for (int kk = 0; kk < 8; ++kk) {
      const size_t qc = ((size_t)(row >> 4) * 8 + kk) * 64 + (row & 15);
      const size_t ac = ((size_t)(lab >> 4) * 8 + kk) * 64 + (lab & 15);
      #pragma unroll
      for (int qd = 0; qd < 4; ++qd) {
        bf16x8 qv = qb[qc + qd * 16];
        bf16x8 av = bb[ac + qd * 16];
        #pragma unroll
        for (int j = 0; j < 8; ++j) dot = fmaf(bf2f(qv[j]), bf2f(av[j]), dot);
      }
    }
    slabws[row] = fmaf(dot, 2.f * L2E, cb[lab]);
  }
}

// ---------------------------------------------------------------------------
// merge: 16384 rows, one thread each; 8-way chunk merge + loss/prec1 finalize.
// ---------------------------------------------------------------------------
__global__ __launch_bounds__(256) void proto_merge(
    const float* __restrict__ partm, const float* __restrict__ parts,
    const int* __restrict__ partbi, const float* __restrict__ slabws,
    const int* __restrict__ label,
    float* __restrict__ accum, int* __restrict__ fincount,
    float* __restrict__ out) {
  const int tid = threadIdx.x, row = blockIdx.x * 256 + tid;
  const int wid = tid >> 6;

  float mm = partm[row], sv = parts[row];
  int   b  = partbi[row];
  #pragma unroll
  for (int c = 1; c < 8; ++c) {                      // chunks in ascending cols
    float om = partm[c * NROW + row], os = parts[c * NROW + row];
    int   oi = partbi[c * NROW + row];
    float nm = fmaxf(mm, om);
    sv = sv * exp2f(mm - nm) + os * exp2f(om - nm);
    bool better = (om > mm) || (om == mm && oi < b);
    b = better ? oi : b;
    mm = nm;
  }

  const int lb = label[row >> 3];
  float loss = LN2 * (mm + log2f(sv) - slabws[row]);
  float corr = (b == lb) ? 1.f : 0.f;

  #pragma unroll
  for (int mask = 32; mask; mask >>= 1) {
    loss += __shfl_xor(loss, mask);
    corr += __shfl_xor(corr, mask);
  }
  __shared__ float red[2][4];
  if ((tid & 63) == 0) { red[0][wid] = loss; red[1][wid] = corr; }
  __syncthreads();
  if (tid == 0) {
    float L = red[0][0] + red[0][1] + red[0][2] + red[0][3];
    float C = red[1][0] + red[1][1] + red[1][2] + red[1][3];
    atomicAdd(&accum[0], L);
    atomicAdd(&accum[1], C);
    __threadfence();
    if (atomicAdd(fincount, 1) == (int)gridDim.x - 1) {
      out[0] = atomicAdd(&accum[0], 0.f) / (float)NROW;     // coherent reads
      out[1] = atomicAdd(&accum[1], 0.f) * 100.f / (float)NROW;
    }
  }
}

// ---------------------------------------------------------------------------
extern "C" void kernel_launch(void* const* d_in, const int* in_sizes, int n_in,
                              void* d_out, int out_size, void* d_ws, size_t ws_size,
                              hipStream_t stream) {
  const float* x     = (const float*)d_in[0];
  const int*   label = (const int*)d_in[1];
  float* out = (float*)d_out;

  // ws layout (float-sized slots): [0:2) accum | [2] fincount |
  // [16,16+NCOL) cb | Asw (NCOL*DD ushort) | Qsw (NROW*DD ushort) |
  // partm[8*NROW] | parts[8*NROW] | partbi[8*NROW] | slab[NROW]  (~1.6 MB)
  float*  W        = (float*)d_ws;
  float*  accum    = W;
  int*    fincount = (int*)(W + 2);
  float*  cb       = W + 16;
  ushort* Asw      = (ushort*)(cb + NCOL);
  ushort* Qsw      = Asw + (size_t)NCOL * DD;
  float*  partm    = (float*)(Qsw + (size_t)NROW * DD);
  float*  parts    = partm + 8 * NROW;
  int*    partbi   = (int*)(parts + 8 * NROW);
  float*  slabws   = (float*)(partbi + 8 * NROW);

  hipLaunchKernelGGL(proto_prep, dim3(NEP / 4), dim3(256), 0, stream,
                     x, cb, Asw, Qsw, accum, fincount);
  hipLaunchKernelGGL(proto_main, dim3(512), dim3(256), 0, stream,
                     Qsw, Asw, cb, label, partm, parts, partbi, slabws);
  hipLaunchKernelGGL(proto_merge, dim3(NROW / 256), dim3(256), 0, stream,
                     partm, parts, partbi, slabws, label, accum, fincount, out);
}